// Round 2
// baseline (769.710 us; speedup 1.0000x reference)
//
#include <hip/hip_runtime.h>
#include <stdint.h>

namespace {

constexpr int Bn = 8;
constexpr int Sn = 2048;
constexpr int Cn = 1024;
constexpr int Mn = Bn * Sn;  // 16384

typedef float f32x4 __attribute__((ext_vector_type(4)));
typedef __bf16 bf16x8 __attribute__((ext_vector_type(8)));
typedef unsigned short us8 __attribute__((ext_vector_type(8)));

__device__ __forceinline__ unsigned short f2bf(float f) {
  uint32_t x = __float_as_uint(f);
  x += 0x7fffu + ((x >> 16) & 1u);  // round-to-nearest-even
  return (unsigned short)(x >> 16);
}
__device__ __forceinline__ float bf2f(unsigned short u) {
  return __uint_as_float(((uint32_t)u) << 16);
}

__device__ __forceinline__ void stage16(const unsigned short* g, unsigned short* l) {
  __builtin_amdgcn_global_load_lds(
      (const __attribute__((address_space(1))) void*)g,
      (__attribute__((address_space(3))) void*)l, 16, 0, 0);
}

// SRC modes for one GEMM operand side:
//   0 = pre-split bf16, hi only   (global_load_lds)
//   1 = pre-split bf16, hi + lo   (global_load_lds x2)
//   2 = fp32 -> split hi/lo       (reg stage + convert + ds_write)
//   3 = fp32 -> hi only           (reg stage + convert + ds_write)
template <int SRC>
__device__ __forceinline__ void stage_side(const void* G0, const void* G1,
                                           long long goff, int ld, int k0, int tbase,
                                           int t, unsigned short* Ls,
                                           unsigned short* Ls2) {
#pragma unroll
  for (int c = 0; c < 2; ++c) {
    int idx = c * 256 + t;
    int row = idx >> 2;
    int co = (idx & 3) * 8;
    long long off = goff + (long long)(tbase + row) * ld + k0 + co;
    if constexpr (SRC <= 1) {
      stage16((const unsigned short*)G0 + off, Ls + idx * 8);
      if constexpr (SRC == 1) stage16((const unsigned short*)G1 + off, Ls2 + idx * 8);
    } else {
      const float* g = (const float*)G0 + off;
      float4 u0 = *(const float4*)g;
      float4 u1 = *(const float4*)(g + 4);
      float f[8] = {u0.x, u0.y, u0.z, u0.w, u1.x, u1.y, u1.z, u1.w};
      us8 h, lo;
#pragma unroll
      for (int j = 0; j < 8; ++j) {
        h[j] = f2bf(f[j]);
        if constexpr (SRC == 2) lo[j] = f2bf(f[j] - bf2f(h[j]));
      }
      *(us8*)&Ls[idx * 8] = h;
      if constexpr (SRC == 2) *(us8*)&Ls2[idx * 8] = lo;
    }
  }
}

// C = A * B^T (+bias). A:[M,K], B^T:[N,K]. 128x128 tile, BK=32, 4 waves,
// 16x16x32 bf16 MFMA. Split (3-term hi/lo emulation) iff the A-side has lo.
// BIAS: 0 none, 1 per-col, 2 per-row.  OUTM: 0 f32, 1 bf16, 2 split bf16 hi/lo.
template <int ASRC, int BSRC, int BIAS, int OUTM>
__global__ __launch_bounds__(256) void gemm(
    const void* __restrict__ A0, const void* __restrict__ A1,
    const void* __restrict__ B0, const void* __restrict__ B1,
    const float* __restrict__ bias, void* __restrict__ C0, void* __restrict__ C1,
    int K, int lda, int ldb, int ldc,
    long long sAz, long long sBz, long long sCz) {
  constexpr bool SPL = (ASRC == 1 || ASRC == 2);
  __shared__ unsigned short smem[SPL ? 16384 : 8192];
  unsigned short* As = smem;
  unsigned short* Bs = smem + 4096;
  unsigned short* As2 = SPL ? smem + 8192 : nullptr;
  unsigned short* Bs2 = SPL ? smem + 12288 : nullptr;

  const int z = blockIdx.z;
  const long long aoff = (long long)z * sAz;
  const long long boff = (long long)z * sBz;
  const long long coff = (long long)z * sCz;
  const int tN = blockIdx.x * 128;
  const int tM = blockIdx.y * 128;
  const int t = threadIdx.x;
  const int l = t & 63;
  const int w = t >> 6;
  const int wr = w >> 1, wc = w & 1;
  const int lr = l & 15;
  const int lk = (l >> 4) * 8;

  f32x4 acc[4][4] = {};

  for (int k0 = 0; k0 < K; k0 += 32) {
    stage_side<ASRC>(A0, A1, aoff, lda, k0, tM, t, As, As2);
    stage_side<BSRC>(B0, B1, boff, ldb, k0, tN, t, Bs, Bs2);
    __syncthreads();
    bf16x8 a0[4], b0[4], a1[4], b1[4];
#pragma unroll
    for (int i = 0; i < 4; ++i) {
      a0[i] = *(const bf16x8*)&As[(wr * 64 + i * 16 + lr) * 32 + lk];
      b0[i] = *(const bf16x8*)&Bs[(wc * 64 + i * 16 + lr) * 32 + lk];
      if constexpr (SPL) {
        a1[i] = *(const bf16x8*)&As2[(wr * 64 + i * 16 + lr) * 32 + lk];
        b1[i] = *(const bf16x8*)&Bs2[(wc * 64 + i * 16 + lr) * 32 + lk];
      }
    }
#pragma unroll
    for (int mi = 0; mi < 4; ++mi)
#pragma unroll
      for (int ni = 0; ni < 4; ++ni) {
        acc[mi][ni] = __builtin_amdgcn_mfma_f32_16x16x32_bf16(a0[mi], b0[ni], acc[mi][ni], 0, 0, 0);
        if constexpr (SPL) {
          acc[mi][ni] = __builtin_amdgcn_mfma_f32_16x16x32_bf16(a0[mi], b1[ni], acc[mi][ni], 0, 0, 0);
          acc[mi][ni] = __builtin_amdgcn_mfma_f32_16x16x32_bf16(a1[mi], b0[ni], acc[mi][ni], 0, 0, 0);
        }
      }
    __syncthreads();
  }

#pragma unroll
  for (int mi = 0; mi < 4; ++mi)
#pragma unroll
    for (int ni = 0; ni < 4; ++ni)
#pragma unroll
      for (int r = 0; r < 4; ++r) {
        int rg = tM + wr * 64 + mi * 16 + (l >> 4) * 4 + r;
        int cg = tN + wc * 64 + ni * 16 + lr;
        float v = acc[mi][ni][r];
        if constexpr (BIAS == 1) v += bias[cg];
        if constexpr (BIAS == 2) v += bias[rg];
        long long off = coff + (long long)rg * ldc + cg;
        if constexpr (OUTM == 0) {
          ((float*)C0)[off] = v;
        } else if constexpr (OUTM == 1) {
          ((unsigned short*)C0)[off] = f2bf(v);
        } else {
          unsigned short h = f2bf(v);
          ((unsigned short*)C0)[off] = h;
          ((unsigned short*)C1)[off] = f2bf(v - bf2f(h));
        }
      }
}

// In-place row softmax: reads fp32 row [Sn], writes normalized bf16 attn into
// the first Sn shorts (= first half) of the same row. All global reads complete
// before the first __syncthreads; all writes happen after the second -> safe.
__global__ __launch_bounds__(256) void k_softmax(float* __restrict__ S) {
  const long long row = blockIdx.x;
  float* src = S + row * Sn;
  const int t = threadIdx.x;
  float4 v0 = *(const float4*)(src + t * 8);
  float4 v1 = *(const float4*)(src + t * 8 + 4);
  float m = fmaxf(fmaxf(fmaxf(v0.x, v0.y), fmaxf(v0.z, v0.w)),
                  fmaxf(fmaxf(v1.x, v1.y), fmaxf(v1.z, v1.w)));
#pragma unroll
  for (int off = 32; off > 0; off >>= 1) m = fmaxf(m, __shfl_xor(m, off));
  __shared__ float red[8];
  if ((t & 63) == 0) red[t >> 6] = m;
  __syncthreads();
  m = fmaxf(fmaxf(red[0], red[1]), fmaxf(red[2], red[3]));
  float e[8];
  e[0] = __expf(v0.x - m); e[1] = __expf(v0.y - m);
  e[2] = __expf(v0.z - m); e[3] = __expf(v0.w - m);
  e[4] = __expf(v1.x - m); e[5] = __expf(v1.y - m);
  e[6] = __expf(v1.z - m); e[7] = __expf(v1.w - m);
  float s = ((e[0] + e[1]) + (e[2] + e[3])) + ((e[4] + e[5]) + (e[6] + e[7]));
#pragma unroll
  for (int off = 32; off > 0; off >>= 1) s += __shfl_xor(s, off);
  if ((t & 63) == 0) red[4 + (t >> 6)] = s;
  __syncthreads();
  s = (red[4] + red[5]) + (red[6] + red[7]);
  float inv = 1.0f / s;
  us8 o;
#pragma unroll
  for (int j = 0; j < 8; ++j) o[j] = f2bf(e[j] * inv);
  *(us8*)((unsigned short*)src + t * 8) = o;
}

}  // namespace

extern "C" void kernel_launch(void* const* d_in, const int* in_sizes, int n_in,
                              void* d_out, int out_size, void* d_ws, size_t ws_size,
                              hipStream_t stream) {
  (void)in_sizes; (void)n_in; (void)out_size;
  const float* x1 = (const float*)d_in[0];
  const float* x2 = (const float*)d_in[1];
  const float* x3 = (const float*)d_in[2];
  const float* Wq = (const float*)d_in[3];
  const float* bq = (const float*)d_in[4];
  const float* Wk = (const float*)d_in[5];
  const float* bk = (const float*)d_in[6];
  const float* Wv = (const float*)d_in[7];
  const float* bv = (const float*)d_in[8];
  float* out = (float*)d_out;
  char* ws = (char*)d_ws;

  const size_t MiB = 1048576ull;
  // ws layout: kh(32) kl(32) vT(32) scores(zc*16) MiB
  unsigned short* kh = (unsigned short*)(ws);
  unsigned short* kl = (unsigned short*)(ws + 32 * MiB);
  unsigned short* vT = (unsigned short*)(ws + 64 * MiB);
  float* S = (float*)(ws + 96 * MiB);
  int zc = 0;
  for (int z = 8; z >= 1; z >>= 1)
    if (ws_size >= 96 * MiB + (size_t)z * 16 * MiB) { zc = z; break; }
  if (!zc) return;  // ws < 112 MiB: leave output zero (visible failure => ws probe)

  // q hi/lo interleaved per batch inside d_out: batch b occupies bytes
  // [b*8MiB, (b+1)*8MiB) = hi[Sn][Cn] then lo[Sn][Cn]. PV later overwrites
  // batch b's slot only after its q is consumed.
  unsigned short* qh = (unsigned short*)d_out;
  unsigned short* ql = (unsigned short*)((char*)d_out + 4 * MiB);
  const long long QZ = 4ll * 1024 * 1024;  // shorts per batch block (8 MiB)

  // Q = x1 @ Wq^T + bq  (fp32 inputs split-staged, 3-term MFMA, split output)
  dim3 gqk(Cn / 128, Sn / 128, Bn);
  gemm<2, 2, 1, 2><<<gqk, 256, 0, stream>>>(x1, nullptr, Wq, nullptr, bq, qh, ql,
                                            Cn, Cn, Cn, Cn,
                                            (long long)Sn * Cn, 0, QZ);
  // K = x2 @ Wk^T + bk -> kh,kl contiguous in ws
  gemm<2, 2, 1, 2><<<gqk, 256, 0, stream>>>(x2, nullptr, Wk, nullptr, bk, kh, kl,
                                            Cn, Cn, Cn, Cn,
                                            (long long)Sn * Cn, 0, (long long)Sn * Cn);
  // vT[d][b*Sn+s] = (x3 @ Wv^T + bv)^T computed directly: A=Wv, B^T=x3, row bias
  dim3 gv(Mn / 128, Cn / 128, 1);
  gemm<3, 3, 2, 1><<<gv, 256, 0, stream>>>(Wv, nullptr, x3, nullptr, bv, vT, nullptr,
                                           Cn, Cn, Cn, Mn, 0, 0, 0);

  for (int b0 = 0; b0 < Bn; b0 += zc) {
    // scores[b] = q[b] @ k[b]^T (split precision, fp32 out, NO 1/sqrt(d))
    dim3 gs(Sn / 128, Sn / 128, zc);
    gemm<1, 1, 0, 0><<<gs, 256, 0, stream>>>(
        qh + (long long)b0 * QZ, ql + (long long)b0 * QZ,
        kh + (long long)b0 * Sn * Cn, kl + (long long)b0 * Sn * Cn, nullptr,
        S, nullptr, Cn, Cn, Cn, Sn, QZ, (long long)Sn * Cn, (long long)Sn * Sn);
    // in-place softmax -> bf16 attn rows (lda becomes 2*Sn shorts)
    k_softmax<<<zc * Sn, 256, 0, stream>>>(S);
    // out[b] = attn[b] @ v[b] : A=attn (bf16, stride 2*Sn), B^T=vT cols b*Sn..
    dim3 gp(Cn / 128, Sn / 128, zc);
    gemm<0, 0, 0, 0><<<gp, 256, 0, stream>>>(
        (unsigned short*)S, nullptr, vT + (long long)b0 * Sn, nullptr, nullptr,
        out + (long long)b0 * Sn * Cn, nullptr,
        Sn, 2 * Sn, Mn, Cn,
        (long long)Sn * Sn * 2, (long long)Sn, (long long)Sn * Cn);
  }
}